// Round 2
// baseline (246.750 us; speedup 1.0000x reference)
//
#include <hip/hip_runtime.h>

// ---------------------------------------------------------------------------
// Round 16: attack wave-tail divergence in the 5 layer kernels + merge k_emb
// into k_build.
//  - k_build now counting-sorts the 256 nodes of each bucket by degree and
//    emits offs3[p] = (ebuf_start, ebuf_end, nodeid, 0) in degree order, so
//    each quad-wave processes 16 similar-degree nodes (max ~= avg instead of
//    E[max of 16 Poisson(16)] ~= 26 vs mean 16 -> ~70% idle-lane waste).
//  - emb is computed inside k_build from the LDS-resident permuted edge list
//    (k_emb dispatch and the 12.8 MB pidx round-trip are deleted).
//  - layer kernels read offs3, write to se.z (scattered, L2-absorbed), skip
//    pad entries (nodeid=-1). #pragma unroll 2 on the edge loop for ILP.
// Baseline (r15): 237.9 us. Prediction: ~180-195 us if divergence-bound;
// ~225 us if latency-bound (then pivot to edge-parallel next round).
// ---------------------------------------------------------------------------

#define BCAP 4608      // bucket capacity: mean 4096 + 8 sigma
#define NBMAX 400

__device__ __forceinline__ float sus_f(float x) {
    return x > 0.0f ? __expf(-1.0f / x) : 0.0f;
}

__device__ __forceinline__ float uload(const float* p) {
    return __uint_as_float(__builtin_amdgcn_readfirstlane(__float_as_uint(*p)));
}

// --- pass 1: coarse binning, 4 B packed {src<<8 | dst&255}; block 0 also
// computes G[k][u][c] = sum_w fc3_w2[k][u*16+w] * conv_w[c][w] ---------------
__global__ __launch_bounds__(256) void k_bin(
    const int* __restrict__ src, const int* __restrict__ dst,
    int* __restrict__ gcur, int* __restrict__ ptmp,
    const float* __restrict__ fc3w2, const float* __restrict__ cw,
    float* __restrict__ gbuf,
    int nedges, int nb)
{
    __shared__ int cnt[NBMAX];
    __shared__ int gb[NBMAX];
    for (int b = threadIdx.x; b < nb; b += 256) cnt[b] = 0;
    __syncthreads();

    int base = blockIdx.x * 2048 + threadIdx.x * 8;
    int pk[8]; int bk[8]; short r[8];
    int ss[8], dd[8];
    if (base + 7 < nedges) {
        int4 s0 = *(const int4*)&src[base];
        int4 s1 = *(const int4*)&src[base + 4];
        int4 d0 = *(const int4*)&dst[base];
        int4 d1 = *(const int4*)&dst[base + 4];
        ss[0]=s0.x; ss[1]=s0.y; ss[2]=s0.z; ss[3]=s0.w;
        ss[4]=s1.x; ss[5]=s1.y; ss[6]=s1.z; ss[7]=s1.w;
        dd[0]=d0.x; dd[1]=d0.y; dd[2]=d0.z; dd[3]=d0.w;
        dd[4]=d1.x; dd[5]=d1.y; dd[6]=d1.z; dd[7]=d1.w;
        #pragma unroll
        for (int i = 0; i < 8; ++i) {
            int b = dd[i] >> 8;
            bk[i] = b;
            pk[i] = (ss[i] << 8) | (dd[i] & 255);
            r[i] = (short)atomicAdd(&cnt[b], 1);
        }
    } else {
        #pragma unroll
        for (int i = 0; i < 8; ++i) {
            int e = base + i;
            if (e < nedges) {
                int s = src[e], t = dst[e];
                int b = t >> 8;
                bk[i] = b;
                pk[i] = (s << 8) | (t & 255);
                r[i] = (short)atomicAdd(&cnt[b], 1);
            } else bk[i] = -1;
        }
    }
    __syncthreads();
    for (int b = threadIdx.x; b < nb; b += 256) {
        int c = cnt[b];
        gb[b] = c > 0 ? atomicAdd(&gcur[b], c) : 0;
    }
    __syncthreads();
    #pragma unroll
    for (int i = 0; i < 8; ++i) {
        if (bk[i] >= 0) {
            int p = gb[bk[i]] + (int)r[i];
            if (p < BCAP)   // statistically impossible overflow guard
                ptmp[bk[i] * BCAP + p] = pk[i];
        }
    }

    // fold in the tiny G-precompute (one block, independent of binning data)
    if (blockIdx.x == 0 && threadIdx.x < 128) {
        int idx = threadIdx.x;          // k*8 + u*2 + c
        int k = idx >> 3, u = (idx >> 1) & 3, c = idx & 1;
        float s = 0.0f;
        #pragma unroll
        for (int w = 0; w < 16; ++w)
            s = fmaf(fc3w2[k * 64 + u * 16 + w], cw[c * 16 + w], s);
        gbuf[idx] = s;
    }
}

// --- pass 2: per-bucket histogram/scan/permute + degree-sort + emb ----------
// Produces: offs3[b*256+p] = (ebuf_start, ebuf_end, nodeid|-1, 0), nodes of
// each bucket sorted ascending by degree (counting sort, 64 clamped bins);
// ebuf records (src_as_float, e0, e1, e2) written directly from LDS perm.
__global__ __launch_bounds__(256) void k_build(
    const int* __restrict__ gcur, const int* __restrict__ ptmp,
    const float* __restrict__ pos,
    float4* __restrict__ ebuf, int4* __restrict__ offs3,
    int n, int nb)
{
    int b = blockIdx.x;
    int cnt = gcur[b]; if (cnt > BCAP) cnt = BCAP;

    __shared__ int stage[BCAP];
    __shared__ int perm[BCAP];
    __shared__ int deg[256];
    __shared__ int loffs[256];
    __shared__ int cur[256];
    __shared__ int h2[64];
    __shared__ int s64[64];
    __shared__ int cur2[64];

    const int* tin = ptmp + b * BCAP;
    for (int j = threadIdx.x; j < cnt; j += 256) stage[j] = tin[j];
    deg[threadIdx.x] = 0;
    if (threadIdx.x < 64) h2[threadIdx.x] = 0;
    __syncthreads();

    for (int j = threadIdx.x; j < cnt; j += 256)
        atomicAdd(&deg[stage[j] & 255], 1);
    __syncthreads();

    // exclusive scan deg -> loffs (also primes cur for the permute)
    {
        int t = threadIdx.x;
        int v = deg[t];
        loffs[t] = v; __syncthreads();
        for (int off = 1; off < 256; off <<= 1) {
            int val = (t >= off) ? loffs[t - off] : 0;
            __syncthreads();
            loffs[t] += val;
            __syncthreads();
        }
        int incl = loffs[t];
        __syncthreads();
        loffs[t] = incl - v;
        cur[t] = incl - v;
        __syncthreads();
    }

    // --- degree counting sort: position p in bucket = rank by degree -------
    int nid0 = b << 8;
    int nn = n - nid0; if (nn > 256) nn = 256;
    int t = threadIdx.x;
    int myDeg = (t < nn) ? deg[t] : 0;
    int bin = (t < nn) ? (myDeg > 63 ? 63 : myDeg) : 0;
    atomicAdd(&h2[bin], 1);
    __syncthreads();
    // exclusive scan of h2 (64 bins), all threads participate in barriers
    if (t < 64) s64[t] = h2[t];
    __syncthreads();
    for (int off = 1; off < 64; off <<= 1) {
        int v = (t < 64 && t >= off) ? s64[t - off] : 0;
        __syncthreads();
        if (t < 64) s64[t] += v;
        __syncthreads();
    }
    if (t < 64) cur2[t] = s64[t] - h2[t];
    __syncthreads();
    {
        int p = atomicAdd(&cur2[bin], 1);
        int st = b * BCAP + loffs[t];
        int nid = (t < nn) ? (nid0 + t) : -1;
        offs3[b * 256 + p] = make_int4(st, st + ((t < nn) ? myDeg : 0), nid, 0);
    }

    // --- permute packed edges into dst-sorted order (LDS) ------------------
    for (int j = threadIdx.x; j < cnt; j += 256) {
        int pkd = stage[j];
        perm[atomicAdd(&cur[pkd & 255], 1)] = pkd;
    }
    __syncthreads();

    // --- radial embedding straight out of LDS perm -------------------------
    const float C = 1.14136f * 7.3890560989306495f; // 1.14136 * e^2
    for (int j = threadIdx.x; j < cnt; j += 256) {
        int pkd = perm[j];
        int s = pkd >> 8;
        int tt = nid0 | (pkd & 255);
        float dx = pos[3 * tt + 0] - pos[3 * s + 0];
        float dy = pos[3 * tt + 1] - pos[3 * s + 1];
        float dz = pos[3 * tt + 2] - pos[3 * s + 2];
        float d = sqrtf(dx * dx + dy * dy + dz * dz);
        float e0, e1, e2;
        { float f = (d - 0.75f) * (1.0f / 0.75f);
          e0 = C * sus_f(f + 1.0f) * sus_f(1.0f - f); }
        { float f = (d - 1.50f) * (1.0f / 0.75f);
          e1 = C * sus_f(f + 1.0f) * sus_f(1.0f - f); }
        { float f = (d - 2.25f) * (1.0f / 0.75f);
          e2 = C * sus_f(f + 1.0f) * sus_f(1.0f - f); }
        ebuf[(size_t)b * BCAP + j] = make_float4(__int_as_float(s), e0, e1, e2);
    }
}

// --- layers: edge-split quads over degree-sorted positions ------------------

__global__ __launch_bounds__(256) void k_node_l1(
    const float* __restrict__ feat, const float4* __restrict__ edata,
    const int4* __restrict__ offs3,
    const float* __restrict__ w1, const float* __restrict__ w2,
    float* __restrict__ xout)
{
    __shared__ float lw[16 * 20];
    if (threadIdx.x < 192) {
        int k = threadIdx.x / 12, r = threadIdx.x % 12;
        lw[k * 20 + r] = w2[k * 12 + r];
    }
    __syncthreads();

    int g = blockIdx.x * 256 + threadIdx.x;
    int p = g >> 2;
    int t = g & 3;
    int4 se = offs3[p];
    if (se.z < 0) return;   // pad entry

    float w1r[3][16];   // wave-uniform -> SGPRs
    #pragma unroll
    for (int j = 0; j < 3; ++j)
        #pragma unroll
        for (int k = 0; k < 16; ++k) w1r[j][k] = uload(&w1[j * 16 + k]);

    float O[16][3];
    #pragma unroll
    for (int k = 0; k < 16; ++k)
        #pragma unroll
        for (int u = 0; u < 3; ++u) O[k][u] = 0.0f;

    #pragma unroll 2
    for (int e = se.x + t; e < se.y; e += 4) {
        float4 ed = edata[e];
        int s = __float_as_int(ed.x);
        float f0 = feat[3 * s + 0], f1 = feat[3 * s + 1], f2 = feat[3 * s + 2];
        #pragma unroll
        for (int k = 0; k < 16; ++k) {
            float a = fmaf(ed.y, w1r[0][k], fmaf(ed.z, w1r[1][k], ed.w * w1r[2][k]));
            float h = a > 0.0f ? a : 0.0f;
            O[k][0] = fmaf(h, f0, O[k][0]);
            O[k][1] = fmaf(h, f1, O[k][1]);
            O[k][2] = fmaf(h, f2, O[k][2]);
        }
    }

    float p0 = 0.f, p1 = 0.f, p2 = 0.f, p3 = 0.f;
    #pragma unroll
    for (int k = 0; k < 16; ++k)
        #pragma unroll
        for (int u = 0; u < 3; ++u) {
            const float4 q = *(const float4*)&lw[k * 20 + u * 4];
            float o = O[k][u];
            p0 = fmaf(o, q.x, p0); p1 = fmaf(o, q.y, p1);
            p2 = fmaf(o, q.z, p2); p3 = fmaf(o, q.w, p3);
        }
    p0 += __shfl_xor(p0, 1); p1 += __shfl_xor(p1, 1);
    p2 += __shfl_xor(p2, 1); p3 += __shfl_xor(p3, 1);
    p0 += __shfl_xor(p0, 2); p1 += __shfl_xor(p1, 2);
    p2 += __shfl_xor(p2, 2); p3 += __shfl_xor(p3, 2);
    if (t == 0) {
        const float S = 0.051031036307982884f; // sqrt2/sqrt3/16
        float4 o; o.x = p0 * S; o.y = p1 * S; o.z = p2 * S; o.w = p3 * S;
        ((float4*)xout)[se.z] = o;
    }
}

__global__ __launch_bounds__(256) void k_node_core(
    const float4* __restrict__ xin, const float4* __restrict__ edata,
    const int4* __restrict__ offs3,
    const float* __restrict__ w1, const float* __restrict__ w2,
    float* __restrict__ xout)
{
    __shared__ float lw[16 * 20];
    {
        int idx = threadIdx.x;
        int k = idx >> 4, r = idx & 15;
        lw[k * 20 + r] = w2[k * 48 + r];
    }
    __syncthreads();

    int g = blockIdx.x * 256 + threadIdx.x;
    int p = g >> 2;
    int t = g & 3;
    int4 se = offs3[p];
    if (se.z < 0) return;   // pad entry

    float w1r[3][16];   // wave-uniform -> SGPRs
    #pragma unroll
    for (int j = 0; j < 3; ++j)
        #pragma unroll
        for (int k = 0; k < 16; ++k) w1r[j][k] = uload(&w1[j * 16 + k]);

    float O[16][4];
    #pragma unroll
    for (int k = 0; k < 16; ++k)
        #pragma unroll
        for (int u = 0; u < 4; ++u) O[k][u] = 0.0f;

    #pragma unroll 2
    for (int e = se.x + t; e < se.y; e += 4) {
        float4 ed = edata[e];
        int s = __float_as_int(ed.x);
        float4 x = xin[s];
        #pragma unroll
        for (int k = 0; k < 16; ++k) {
            float a = fmaf(ed.y, w1r[0][k], fmaf(ed.z, w1r[1][k], ed.w * w1r[2][k]));
            float h = a > 0.0f ? a : 0.0f;
            O[k][0] = fmaf(h, x.x, O[k][0]);
            O[k][1] = fmaf(h, x.y, O[k][1]);
            O[k][2] = fmaf(h, x.z, O[k][2]);
            O[k][3] = fmaf(h, x.w, O[k][3]);
        }
    }

    float p0 = 0.f, p1 = 0.f, p2 = 0.f, p3 = 0.f;
    #pragma unroll
    for (int k = 0; k < 16; ++k)
        #pragma unroll
        for (int u = 0; u < 4; ++u) {
            const float4 q = *(const float4*)&lw[k * 20 + u * 4];
            float o = O[k][u];
            p0 = fmaf(o, q.x, p0); p1 = fmaf(o, q.y, p1);
            p2 = fmaf(o, q.z, p2); p3 = fmaf(o, q.w, p3);
        }
    p0 += __shfl_xor(p0, 1); p1 += __shfl_xor(p1, 1);
    p2 += __shfl_xor(p2, 1); p3 += __shfl_xor(p3, 1);
    p0 += __shfl_xor(p0, 2); p1 += __shfl_xor(p1, 2);
    p2 += __shfl_xor(p2, 2); p3 += __shfl_xor(p3, 2);
    if (t == 0) {
        const float S = 0.04419417382415922f; // sqrt2*0.5/16
        float4 o; o.x = p0 * S; o.y = p1 * S; o.z = p2 * S; o.w = p3 * S;
        ((float4*)xout)[se.z] = o;
    }
}

// fc3 + folded 1x1 conv via precomputed G[16][4][2].
__global__ __launch_bounds__(256) void k_node_fc3_final(
    const float4* __restrict__ xin, const float4* __restrict__ edata,
    const int4* __restrict__ offs3,
    const float* __restrict__ w1, const float* __restrict__ gbuf,
    const float* __restrict__ cb,
    float* __restrict__ out)
{
    __shared__ float lg[128];
    if (threadIdx.x < 128) lg[threadIdx.x] = gbuf[threadIdx.x];
    __syncthreads();

    int g = blockIdx.x * 256 + threadIdx.x;
    int p = g >> 2;
    int t = g & 3;
    int4 se = offs3[p];
    if (se.z < 0) return;   // pad entry

    float w1r[3][16];   // wave-uniform -> SGPRs
    #pragma unroll
    for (int j = 0; j < 3; ++j)
        #pragma unroll
        for (int k = 0; k < 16; ++k) w1r[j][k] = uload(&w1[j * 16 + k]);

    float O[16][4];
    #pragma unroll
    for (int k = 0; k < 16; ++k)
        #pragma unroll
        for (int u = 0; u < 4; ++u) O[k][u] = 0.0f;

    #pragma unroll 2
    for (int e = se.x + t; e < se.y; e += 4) {
        float4 ed = edata[e];
        int s = __float_as_int(ed.x);
        float4 x = xin[s];
        #pragma unroll
        for (int k = 0; k < 16; ++k) {
            float a = fmaf(ed.y, w1r[0][k], fmaf(ed.z, w1r[1][k], ed.w * w1r[2][k]));
            float h = a > 0.0f ? a : 0.0f;
            O[k][0] = fmaf(h, x.x, O[k][0]);
            O[k][1] = fmaf(h, x.y, O[k][1]);
            O[k][2] = fmaf(h, x.z, O[k][2]);
            O[k][3] = fmaf(h, x.w, O[k][3]);
        }
    }

    float a0 = 0.f, a1 = 0.f;
    #pragma unroll
    for (int k = 0; k < 16; ++k)
        #pragma unroll
        for (int u = 0; u < 4; ++u) {
            float o = O[k][u];
            const float2 q = *(const float2*)&lg[(k * 4 + u) * 2];
            a0 = fmaf(o, q.x, a0);
            a1 = fmaf(o, q.y, a1);
        }
    a0 += __shfl_xor(a0, 1); a1 += __shfl_xor(a1, 1);
    a0 += __shfl_xor(a0, 2); a1 += __shfl_xor(a1, 2);
    if (t == 0) {
        const float S = 0.04419417382415922f;
        float2 o; o.x = fmaf(a0, S, cb[0]); o.y = fmaf(a1, S, cb[1]);
        ((float2*)out)[se.z] = o;
    }
}

// ---------------------------------------------------------------------------

extern "C" void kernel_launch(void* const* d_in, const int* in_sizes, int n_in,
                              void* d_out, int out_size, void* d_ws, size_t ws_size,
                              hipStream_t stream) {
    const float* pos     = (const float*)d_in[0];
    const float* feat    = (const float*)d_in[1];
    const int*   esrc    = (const int*)d_in[2];
    const int*   edst    = (const int*)d_in[3];
    const float* fc1_w1  = (const float*)d_in[4];
    const float* fc1_w2  = (const float*)d_in[5];
    const float* core_w1 = (const float*)d_in[6];
    const float* core_w2 = (const float*)d_in[7];
    const float* fc3_w1  = (const float*)d_in[8];
    const float* fc3_w2  = (const float*)d_in[9];
    const float* conv_w  = (const float*)d_in[10];
    const float* conv_b  = (const float*)d_in[11];
    float* out = (float*)d_out;

    const int E = in_sizes[2];          // 1600000
    const int N = in_sizes[0] / 3;      // 100000
    const int nb = (N + 255) >> 8;      // 391

    float4* ebuf = (float4*)d_ws;                        // nb*BCAP float4
    int* ptmp  = (int*)(ebuf + (size_t)nb * BCAP);       // nb*BCAP int
    float* xa  = (float*)(ptmp + (size_t)nb * BCAP);     // 4N
    float* xb  = xa + (size_t)4 * N;                     // 4N
    int4* offs3 = (int4*)(xb + (size_t)4 * N);           // nb*256 int4
    int* gcur  = (int*)(offs3 + (size_t)nb * 256);       // nb
    float* gbuf = (float*)(gcur + ((nb + 3) & ~3));      // 128

    int gp = nb * 4;   // nb*256 positions, 4 lanes each, 256 threads/block

    hipMemsetAsync(gcur, 0, (size_t)nb * sizeof(int), stream);
    k_bin<<<(E + 2047) / 2048, 256, 0, stream>>>(esrc, edst, gcur, ptmp,
                                                 fc3_w2, conv_w, gbuf, E, nb);
    k_build<<<nb, 256, 0, stream>>>(gcur, ptmp, pos, ebuf, offs3, N, nb);

    k_node_l1<<<gp, 256, 0, stream>>>(feat, ebuf, offs3, fc1_w1, fc1_w2, xa);
    k_node_core<<<gp, 256, 0, stream>>>((const float4*)xa, ebuf, offs3,
                                        core_w1 + 0, core_w2 + 0, xb);
    k_node_core<<<gp, 256, 0, stream>>>((const float4*)xb, ebuf, offs3,
                                        core_w1 + 48, core_w2 + 768, xa);
    k_node_core<<<gp, 256, 0, stream>>>((const float4*)xa, ebuf, offs3,
                                        core_w1 + 96, core_w2 + 1536, xb);
    k_node_fc3_final<<<gp, 256, 0, stream>>>((const float4*)xb, ebuf, offs3,
                                             fc3_w1, gbuf, conv_b, out);
}